// Round 21
// baseline (41.317 us; speedup 1.0000x reference)
//
#include <hip/hip_runtime.h>

// VectorQuantizer on MI355X (gfx950) — fp16 MFMA scan + exact rescore, r20.
// r19 (best, 40.1us) with the per-block staging prologue replaced by a prep
// kernel: vq_prep computes the SAME bits (fp16(-512e) swizzled image,
// 256*(es+0.5), exact esum) once into d_ws; main blocks copy 64KB verbatim
// (8 uint4/thread) instead of reading 128KB f32 + ~150 convert/esum VALU ops
// behind a barrier. Scan/skip/rescore/write code byte-identical to r19 ->
// outputs bit-identical.

#define C_DIM   64
#define N_EMB   512
#define HW      4096
#define N_PIX   (32 * HW)            // 131072
#define ZQ_OFF  1
#define IDX_OFF (1 + N_PIX * C_DIM)
#define NBLK    512                  // 256 px per block
#define TPB     512                  // 8 waves x 32 px
// d_ws layout (floats): [0..16384) cb16 swizzled image (64KB as u32),
// [16384..16896) esh5=256*(es+0.5), [16896..17408) exact esum,
// [17408..17920) per-block loss partials
#define WS_ESH5 16384
#define WS_ESHX 16896
#define WS_LOSS 17408

typedef _Float16 half8 __attribute__((ext_vector_type(8)));
typedef float    f32x4 __attribute__((ext_vector_type(4)));
union FragH { unsigned u[4]; half8 h8; uint4 u4; _Float16 h[8]; };

__device__ __forceinline__ unsigned umn(unsigned a, unsigned b){ return a<b?a:b; }
__device__ __forceinline__ unsigned umx(unsigned a, unsigned b){ return a>b?a:b; }
__device__ __forceinline__ unsigned med3u(unsigned a, unsigned b, unsigned c){
    unsigned r;
    asm("v_med3_u32 %0, %1, %2, %3" : "=v"(r) : "v"(a), "v"(b), "v"(c));
    return r;
}

// ---- prep: thread = code j; same arithmetic as r19's per-block staging ----
__global__ __launch_bounds__(64) void vq_prep(
    const float* __restrict__ cb, float* __restrict__ wsf)
{
    const int j = blockIdx.x * 64 + threadIdx.x;      // 0..511
    const float* e = cb + j * C_DIM;
    float ev[64];
    #pragma unroll
    for (int q = 0; q < 16; ++q) {
        float4 v = ((const float4*)e)[q];
        ev[4*q+0]=v.x; ev[4*q+1]=v.y; ev[4*q+2]=v.z; ev[4*q+3]=v.w;
    }
    // numpy pairwise_sum(n=64): 8 accs, rounded mul, tree combine
    float r[8];
    #pragma unroll
    for (int i = 0; i < 8; ++i) r[i] = __fmul_rn(ev[i], ev[i]);
    #pragma unroll
    for (int k = 8; k < 64; k += 8) {
        #pragma unroll
        for (int i = 0; i < 8; ++i)
            r[i] = __fadd_rn(r[i], __fmul_rn(ev[k+i], ev[k+i]));
    }
    float es = __fadd_rn(
        __fadd_rn(__fadd_rn(r[0],r[1]), __fadd_rn(r[2],r[3])),
        __fadd_rn(__fadd_rn(r[4],r[5]), __fadd_rn(r[6],r[7])));
    wsf[WS_ESHX + j] = es;
    wsf[WS_ESH5 + j] = __fmul_rn(__fadd_rn(es, 0.5f), 256.0f);  // x256 exact
    unsigned hw_[32];
    #pragma unroll
    for (int w2 = 0; w2 < 32; ++w2) {
        union { _Float16 hh[2]; unsigned u; } pk;
        pk.hh[0] = (_Float16)(ev[2*w2]   * -512.0f);            // negated
        pk.hh[1] = (_Float16)(ev[2*w2+1] * -512.0f);
        hw_[w2] = pk.u;
    }
    const int rs = j & 7;
    unsigned* img = (unsigned*)wsf;
    #pragma unroll
    for (int g = 0; g < 8; ++g) {
        int g2 = g ^ rs;
        *(uint4*)&img[j*32 + g2*4] =
            make_uint4(hw_[4*g], hw_[4*g+1], hw_[4*g+2], hw_[4*g+3]);
    }
}

__global__ __launch_bounds__(TPB, 4) void vq_main(
    const float* __restrict__ z,
    const float* __restrict__ cb,
    float* __restrict__ out,
    float* __restrict__ wsf)
{
    __shared__ unsigned cbh[N_EMB * 32];   // 64KB swizzled fp16(-512e) image
    __shared__ float    esh5[N_EMB];       // 256*(es+0.5)  (MFMA C-init)
    __shared__ float    eshx[N_EMB];       // numpy-exact esum (rescore)
    __shared__ float    wsum[8];

    const int t = threadIdx.x;             // 0..511

    // ---- Prologue: verbatim 64KB copy + tables (prep did all the math) ----
    {
        const uint4* srcv = (const uint4*)wsf;
        uint4* dstv = (uint4*)cbh;
        #pragma unroll
        for (int i = 0; i < 8; ++i)
            dstv[t + i * TPB] = srcv[t + i * TPB];
        esh5[t] = wsf[WS_ESH5 + t];
        eshx[t] = wsf[WS_ESHX + t];
    }
    __syncthreads();

    const int l   = t & 63;
    const int wv  = t >> 6;                // wave 0..7
    const int lg  = l >> 4;                // k-chunk / candidate group 0..3
    const int li  = l & 15;                // pixel col / code row in tile
    const int bb  = blockIdx.x >> 4;       // batch (256 px/block, 4096 px/image)
    const int g20 = (lg)     ^ (li & 7);
    const int g21 = (4 + lg) ^ (li & 7);
    const int jb  = lg * 4;
    float ls = 0.f;

    // ---- Wave covers 32 consecutive px: tile A = +li, tile B = +16+li ----
    const int pxw0 = blockIdx.x * 256 + wv * 32;
    const float* zbA = z + (size_t)bb * (C_DIM * HW) + ((pxw0      + li) & (HW-1));
    const float* zbB = z + (size_t)bb * (C_DIM * HW) + ((pxw0 + 16 + li) & (HW-1));

    FragH bA0, bA1, bB0, bB1;
    float apxA = 0.f, apxB = 0.f;
    {
        const float* c0 = zbA + (size_t)(lg*8) * HW;
        const float* c1 = zbA + (size_t)(32 + lg*8) * HW;
        const float* c2 = zbB + (size_t)(lg*8) * HW;
        const float* c3 = zbB + (size_t)(32 + lg*8) * HW;
        #pragma unroll
        for (int i = 0; i < 8; ++i) {
            float x0 = c0[(size_t)i*HW], x1 = c1[(size_t)i*HW];
            float y0 = c2[(size_t)i*HW], y1 = c3[(size_t)i*HW];
            bA0.h[i] = (_Float16)x0;  bA1.h[i] = (_Float16)x1;
            bB0.h[i] = (_Float16)y0;  bB1.h[i] = (_Float16)y1;
            apxA = __fmaf_rn(x0, x0, apxA); apxA = __fmaf_rn(x1, x1, apxA);
            apxB = __fmaf_rn(y0, y0, apxB); apxB = __fmaf_rn(y1, y1, apxB);
        }
        apxA += __shfl_xor(apxA, 16, 64);  apxA += __shfl_xor(apxA, 32, 64);
        apxB += __shfl_xor(apxB, 16, 64);  apxB += __shfl_xor(apxB, 32, 64);
    }

    // ---- MFMA scan: shared a-frags/esh5; two independent acc chains ----
    unsigned sA1[4], sA2[4], sA3[4], sB1[4], sB2[4], sB3[4];
    #pragma unroll
    for (int i = 0; i < 4; ++i) {
        sA1[i]=sA2[i]=sA3[i]=0xFFFFFFFFu;
        sB1[i]=sB2[i]=sB3[i]=0xFFFFFFFFu;
    }
    #pragma unroll 4
    for (int T = 0; T < 32; ++T) {
        const int row = T*16 + li;
        FragH a0, a1;
        a0.u4 = *(const uint4*)&cbh[row*32 + g20*4];
        a1.u4 = *(const uint4*)&cbh[row*32 + g21*4];
        f32x4 es = *(const f32x4*)&esh5[T*16 + jb];   // shared C-init
        f32x4 accA = es, accB = es;
        accA = __builtin_amdgcn_mfma_f32_16x16x32_f16(a0.h8, bA0.h8, accA, 0,0,0);
        accB = __builtin_amdgcn_mfma_f32_16x16x32_f16(a0.h8, bB0.h8, accB, 0,0,0);
        accA = __builtin_amdgcn_mfma_f32_16x16x32_f16(a1.h8, bA1.h8, accA, 0,0,0);
        accB = __builtin_amdgcn_mfma_f32_16x16x32_f16(a1.h8, bB1.h8, accB, 0,0,0);
        const int jT = T*16 + jb;
        #pragma unroll
        for (int r2 = 0; r2 < 4; ++r2) {
            unsigned keyA = (__float_as_uint(accA[r2]) & 0xFFFFFE00u) | (unsigned)(jT + r2);
            unsigned keyB = (__float_as_uint(accB[r2]) & 0xFFFFFE00u) | (unsigned)(jT + r2);
            unsigned nA3 = med3u(keyA, sA2[r2], sA3[r2]);
            unsigned nA2 = med3u(keyA, sA1[r2], sA2[r2]);
            sA1[r2] = umn(sA1[r2], keyA); sA2[r2] = nA2; sA3[r2] = nA3;
            unsigned nB3 = med3u(keyB, sB2[r2], sB3[r2]);
            unsigned nB2 = med3u(keyB, sB1[r2], sB2[r2]);
            sB1[r2] = umn(sB1[r2], keyB); sB2[r2] = nB2; sB3[r2] = nB3;
        }
    }

    // ---- per-tile: skip decision + (skip | exact rescore) ----
    int bjA, bjB;
    #pragma unroll
    for (int pt = 0; pt < 2; ++pt) {
        unsigned (&s1)[4] = pt ? sB1 : sA1;
        unsigned (&s2)[4] = pt ? sB2 : sA2;
        unsigned (&s3)[4] = pt ? sB3 : sA3;
        const float* zb = pt ? zbB : zbA;
        const float apx = pt ? apxB : apxA;
        const int   px  = pxw0 + pt*16 + li;

        // pixel-global approx top-2
        unsigned m1, m2;
        {
            unsigned p1 = umn(s1[0], s1[1]);
            unsigned p2 = umn(umx(s1[0], s1[1]), umn(s2[0], s2[1]));
            unsigned q1 = umn(s1[2], s1[3]);
            unsigned q2 = umn(umx(s1[2], s1[3]), umn(s2[2], s2[3]));
            m1 = umn(p1, q1);
            m2 = umn(umx(p1, q1), umn(p2, q2));
            #pragma unroll
            for (int m = 16; m <= 32; m <<= 1) {
                unsigned o1 = __shfl_xor(m1, m, 64), o2 = __shfl_xor(m2, m, 64);
                unsigned nm2 = umn(umx(m1, o1), umn(m2, o2));
                m1 = umn(m1, o1); m2 = nm2;
            }
        }
        const float d1m = __uint_as_float(m1 & 0xFFFFFE00u);   // scaled x256
        const float d2m = __uint_as_float(m2 & 0xFFFFFE00u);
        const bool  amb = (d2m - d1m) <= 0.030720f;            // 256 * 1.2e-4

        int bj;
        if (__ballot(amb) == 0ULL) {
            bj = (int)(m1 & 511u);
            if (l < 16) {
                out[IDX_OFF + px] = (float)bj;
                float dd = __uint_as_float((m1 & 0xFFFFFE00u) | 0x100u);
                ls += __fmaf_rn(dd, 0.00390625f, apx - 0.5f);
            }
        } else {
            unsigned k1, k2, k3;
            {
                #define MERGE3(o1,o2,o3, a1,a2,a3, b1,b2,b3)                 \
                    o1 = umn(a1, b1);                                        \
                    o2 = med3u(a1, b1, umn(a2, b2));                         \
                    o3 = umn(umn(a3, b3), umn(umx(a2, b1), umx(a1, b2)));
                unsigned x1,x2,x3, y1,y2,y3;
                MERGE3(x1,x2,x3, s1[0],s2[0],s3[0], s1[1],s2[1],s3[1]);
                MERGE3(y1,y2,y3, s1[2],s2[2],s3[2], s1[3],s2[3],s3[3]);
                MERGE3(k1,k2,k3, x1,x2,x3, y1,y2,y3);
                #undef MERGE3
            }
            float zr[64];
            #pragma unroll
            for (int c = 0; c < 64; ++c) zr[c] = zb[(size_t)c * HW];
            float ap;
            {   // numpy-exact ||z||^2
                float r[8];
                #pragma unroll
                for (int i = 0; i < 8; ++i) r[i] = __fmul_rn(zr[i], zr[i]);
                #pragma unroll
                for (int k = 8; k < 64; k += 8) {
                    #pragma unroll
                    for (int i = 0; i < 8; ++i)
                        r[i] = __fadd_rn(r[i], __fmul_rn(zr[k+i], zr[k+i]));
                }
                ap = __fadd_rn(
                    __fadd_rn(__fadd_rn(r[0],r[1]), __fadd_rn(r[2],r[3])),
                    __fadd_rn(__fadd_rn(r[4],r[5]), __fadd_rn(r[6],r[7])));
            }
            const float thr = d1m + 0.030720f;
            float bd = 3.0e38f; bj = 1023;

            #define RESCORE(K) do {                                               \
                float da_ = __uint_as_float((K) & 0xFFFFFE00u);                   \
                if (da_ <= thr) {                                                 \
                    int j_ = (int)((K) & 511u);                                   \
                    const float* er_ = cb + (size_t)j_ * 64;                      \
                    float a_ = 0.f;                                               \
                    _Pragma("unroll")                                             \
                    for (int c_ = 0; c_ < 64; ++c_)                               \
                        a_ = __fmaf_rn(zr[c_], er_[c_], a_);                      \
                    float dd_ = __fsub_rn(__fadd_rn(ap, eshx[j_]),                \
                                          __fmul_rn(2.0f, a_));                   \
                    if (dd_ < bd || (dd_ == bd && j_ < bj)) { bd = dd_; bj = j_; }\
                }                                                                 \
            } while (0)
            RESCORE(k1); RESCORE(k2); RESCORE(k3);
            #undef RESCORE

            #pragma unroll
            for (int m = 16; m <= 32; m <<= 1) {   // lexicographic (d,j) merge
                float od = __shfl_xor(bd, m, 64);
                int   oj = __shfl_xor(bj, m, 64);
                if (od < bd || (od == bd && oj < bj)) { bd = od; bj = oj; }
            }
            if (l < 16) {
                out[IDX_OFF + px] = (float)bj;
                ls += bd;
            }
        }
        if (pt == 0) bjA = bj; else bjB = bj;
    }

    // ---- z_q write: both tiles together -> full 128B lines ----
    {
        const int pm  = l & 31;
        const int hh  = l >> 5;
        int b0 = __shfl(bjA, pm & 15, 64);
        int b1 = __shfl(bjB, pm & 15, 64);
        const int bjw = (pm >> 4) ? b1 : b0;
        const float* eb = cb + (size_t)bjw * 64;
        float* zq = out + ZQ_OFF + (size_t)bb * (C_DIM * HW) + ((pxw0 + pm) & (HW-1));
        #pragma unroll
        for (int cc = 0; cc < 32; ++cc) {
            int c = hh * 32 + cc;
            zq[(size_t)c * HW] = eb[c];    // 32 px x 2 planes = 2 full lines/instr
        }
    }

    // ---- loss reduce: wave -> block -> ws ----
    #pragma unroll
    for (int off = 32; off; off >>= 1) ls += __shfl_down(ls, off, 64);
    if (l == 0) wsum[wv] = ls;
    __syncthreads();
    if (t == 0) {
        float s = 0.f;
        #pragma unroll
        for (int i = 0; i < 8; ++i) s += wsum[i];
        wsf[WS_LOSS + blockIdx.x] = s;
    }
}

__global__ __launch_bounds__(256) void vq_loss(
    const float* __restrict__ wsf, float* __restrict__ out)
{
    __shared__ float sm[4];
    const float* p = wsf + WS_LOSS;        // 512 block partials
    float v = p[threadIdx.x] + p[threadIdx.x + 256];
    #pragma unroll
    for (int off = 32; off; off >>= 1) v += __shfl_down(v, off, 64);
    const int lane = threadIdx.x & 63, wid = threadIdx.x >> 6;
    if (lane == 0) sm[wid] = v;
    __syncthreads();
    if (threadIdx.x == 0)
        out[0] = ((sm[0] + sm[1]) + (sm[2] + sm[3])) * (1.0f / 8388608.0f);
}

extern "C" void kernel_launch(void* const* d_in, const int* in_sizes, int n_in,
                              void* d_out, int out_size, void* d_ws, size_t ws_size,
                              hipStream_t stream)
{
    const float* z  = (const float*)d_in[0];   // 8388608 f32
    const float* cb = (const float*)d_in[1];   // 32768 f32
    float* out = (float*)d_out;
    float* wsf = (float*)d_ws;                 // ~72KB scratch

    vq_prep<<<8, 64, 0, stream>>>(cb, wsf);
    vq_main<<<NBLK, TPB, 0, stream>>>(z, cb, out, wsf);
    vq_loss<<<1, 256, 0, stream>>>(wsf, out);
}

// Round 22
// 40.586 us; speedup vs baseline: 1.0180x; 1.0180x over previous
//
#include <hip/hip_runtime.h>

// VectorQuantizer on MI355X (gfx950) — fp16 MFMA scan + exact rescore.
// FINAL (= round 19, measured best 40.1us): r18 machinery (acc-init keys,
// per-r2 top-3 chains, per-tile wave-skip, numpy-bit-exact rescore) on the
// 2-tile-per-wave geometry (shared A-frag/esh5 LDS reads, 2x MFMA ILP,
// full-128B-line z_q writes). r20's prep-kernel variant regressed (prologue
// not on critical path) — reverted. Structure is at its latency floor:
// VALU 31% / MFMA 7.4% / HBM 20%, LDS(64KB codebook) caps 2 blocks/CU,
// 9 geometry variants converged to ~40-44us.

#define C_DIM   64
#define N_EMB   512
#define HW      4096
#define N_PIX   (32 * HW)            // 131072
#define ZQ_OFF  1
#define IDX_OFF (1 + N_PIX * C_DIM)
#define NBLK    512                  // 256 px per block
#define TPB     512                  // 8 waves x 32 px

typedef _Float16 half8 __attribute__((ext_vector_type(8)));
typedef float    f32x4 __attribute__((ext_vector_type(4)));
union FragH { unsigned u[4]; half8 h8; uint4 u4; _Float16 h[8]; };

__device__ __forceinline__ unsigned umn(unsigned a, unsigned b){ return a<b?a:b; }
__device__ __forceinline__ unsigned umx(unsigned a, unsigned b){ return a>b?a:b; }
__device__ __forceinline__ unsigned med3u(unsigned a, unsigned b, unsigned c){
    unsigned r;
    asm("v_med3_u32 %0, %1, %2, %3" : "=v"(r) : "v"(a), "v"(b), "v"(c));
    return r;
}

__global__ __launch_bounds__(TPB, 4) void vq_main(
    const float* __restrict__ z,
    const float* __restrict__ cb,
    float* __restrict__ out,
    float* __restrict__ ws)
{
    __shared__ unsigned cbh[N_EMB * 32];   // 64KB codebook fp16(-512e) pairs, swizzled
    __shared__ float    esh5[N_EMB];       // 256*(es+0.5)  (MFMA C-init)
    __shared__ float    eshx[N_EMB];       // numpy-exact esum (rescore)
    __shared__ float    wsum[8];

    const int t = threadIdx.x;             // 0..511: thread t stages code t

    // ---- Stage codebook + numpy-exact esum ----
    {
        const float* e = cb + t * C_DIM;
        float ev[64];
        #pragma unroll
        for (int q = 0; q < 16; ++q) {
            float4 v = ((const float4*)e)[q];
            ev[4*q+0]=v.x; ev[4*q+1]=v.y; ev[4*q+2]=v.z; ev[4*q+3]=v.w;
        }
        float r[8];
        #pragma unroll
        for (int i = 0; i < 8; ++i) r[i] = __fmul_rn(ev[i], ev[i]);
        #pragma unroll
        for (int k = 8; k < 64; k += 8) {
            #pragma unroll
            for (int i = 0; i < 8; ++i)
                r[i] = __fadd_rn(r[i], __fmul_rn(ev[k+i], ev[k+i]));
        }
        float es = __fadd_rn(
            __fadd_rn(__fadd_rn(r[0],r[1]), __fadd_rn(r[2],r[3])),
            __fadd_rn(__fadd_rn(r[4],r[5]), __fadd_rn(r[6],r[7])));
        eshx[t] = es;
        esh5[t] = __fmul_rn(__fadd_rn(es, 0.5f), 256.0f);   // x256 exact (pow2)
        unsigned hw_[32];
        #pragma unroll
        for (int w2 = 0; w2 < 32; ++w2) {
            union { _Float16 hh[2]; unsigned u; } pk;
            pk.hh[0] = (_Float16)(ev[2*w2]   * -512.0f);    // negated
            pk.hh[1] = (_Float16)(ev[2*w2+1] * -512.0f);
            hw_[w2] = pk.u;
        }
        const int rs = t & 7;
        #pragma unroll
        for (int g = 0; g < 8; ++g) {
            int g2 = g ^ rs;
            *(uint4*)&cbh[t*32 + g2*4] =
                make_uint4(hw_[4*g], hw_[4*g+1], hw_[4*g+2], hw_[4*g+3]);
        }
    }
    __syncthreads();

    const int l   = t & 63;
    const int wv  = t >> 6;                // wave 0..7
    const int lg  = l >> 4;                // k-chunk / candidate group 0..3
    const int li  = l & 15;                // pixel col / code row in tile
    const int bb  = blockIdx.x >> 4;       // batch (256 px/block, 4096 px/image)
    const int g20 = (lg)     ^ (li & 7);
    const int g21 = (4 + lg) ^ (li & 7);
    const int jb  = lg * 4;
    float ls = 0.f;

    // ---- Wave covers 32 consecutive px: tile A = +li, tile B = +16+li ----
    const int pxw0 = blockIdx.x * 256 + wv * 32;
    const float* zbA = z + (size_t)bb * (C_DIM * HW) + ((pxw0      + li) & (HW-1));
    const float* zbB = z + (size_t)bb * (C_DIM * HW) + ((pxw0 + 16 + li) & (HW-1));

    FragH bA0, bA1, bB0, bB1;
    float apxA = 0.f, apxB = 0.f;
    {
        const float* c0 = zbA + (size_t)(lg*8) * HW;
        const float* c1 = zbA + (size_t)(32 + lg*8) * HW;
        const float* c2 = zbB + (size_t)(lg*8) * HW;
        const float* c3 = zbB + (size_t)(32 + lg*8) * HW;
        #pragma unroll
        for (int i = 0; i < 8; ++i) {
            float x0 = c0[(size_t)i*HW], x1 = c1[(size_t)i*HW];
            float y0 = c2[(size_t)i*HW], y1 = c3[(size_t)i*HW];
            bA0.h[i] = (_Float16)x0;  bA1.h[i] = (_Float16)x1;
            bB0.h[i] = (_Float16)y0;  bB1.h[i] = (_Float16)y1;
            apxA = __fmaf_rn(x0, x0, apxA); apxA = __fmaf_rn(x1, x1, apxA);
            apxB = __fmaf_rn(y0, y0, apxB); apxB = __fmaf_rn(y1, y1, apxB);
        }
        apxA += __shfl_xor(apxA, 16, 64);  apxA += __shfl_xor(apxA, 32, 64);
        apxB += __shfl_xor(apxB, 16, 64);  apxB += __shfl_xor(apxB, 32, 64);
    }

    // ---- MFMA scan: shared a-frags/esh5; two independent acc chains ----
    unsigned sA1[4], sA2[4], sA3[4], sB1[4], sB2[4], sB3[4];
    #pragma unroll
    for (int i = 0; i < 4; ++i) {
        sA1[i]=sA2[i]=sA3[i]=0xFFFFFFFFu;
        sB1[i]=sB2[i]=sB3[i]=0xFFFFFFFFu;
    }
    #pragma unroll 4
    for (int T = 0; T < 32; ++T) {
        const int row = T*16 + li;
        FragH a0, a1;
        a0.u4 = *(const uint4*)&cbh[row*32 + g20*4];
        a1.u4 = *(const uint4*)&cbh[row*32 + g21*4];
        f32x4 es = *(const f32x4*)&esh5[T*16 + jb];   // shared C-init
        f32x4 accA = es, accB = es;
        accA = __builtin_amdgcn_mfma_f32_16x16x32_f16(a0.h8, bA0.h8, accA, 0,0,0);
        accB = __builtin_amdgcn_mfma_f32_16x16x32_f16(a0.h8, bB0.h8, accB, 0,0,0);
        accA = __builtin_amdgcn_mfma_f32_16x16x32_f16(a1.h8, bA1.h8, accA, 0,0,0);
        accB = __builtin_amdgcn_mfma_f32_16x16x32_f16(a1.h8, bB1.h8, accB, 0,0,0);
        const int jT = T*16 + jb;
        #pragma unroll
        for (int r2 = 0; r2 < 4; ++r2) {
            unsigned keyA = (__float_as_uint(accA[r2]) & 0xFFFFFE00u) | (unsigned)(jT + r2);
            unsigned keyB = (__float_as_uint(accB[r2]) & 0xFFFFFE00u) | (unsigned)(jT + r2);
            unsigned nA3 = med3u(keyA, sA2[r2], sA3[r2]);
            unsigned nA2 = med3u(keyA, sA1[r2], sA2[r2]);
            sA1[r2] = umn(sA1[r2], keyA); sA2[r2] = nA2; sA3[r2] = nA3;
            unsigned nB3 = med3u(keyB, sB2[r2], sB3[r2]);
            unsigned nB2 = med3u(keyB, sB1[r2], sB2[r2]);
            sB1[r2] = umn(sB1[r2], keyB); sB2[r2] = nB2; sB3[r2] = nB3;
        }
    }

    // ---- per-tile: skip decision + (skip | exact rescore) ----
    int bjA, bjB;
    #pragma unroll
    for (int pt = 0; pt < 2; ++pt) {
        unsigned (&s1)[4] = pt ? sB1 : sA1;
        unsigned (&s2)[4] = pt ? sB2 : sA2;
        unsigned (&s3)[4] = pt ? sB3 : sA3;
        const float* zb = pt ? zbB : zbA;
        const float apx = pt ? apxB : apxA;
        const int   px  = pxw0 + pt*16 + li;

        // pixel-global approx top-2
        unsigned m1, m2;
        {
            unsigned p1 = umn(s1[0], s1[1]);
            unsigned p2 = umn(umx(s1[0], s1[1]), umn(s2[0], s2[1]));
            unsigned q1 = umn(s1[2], s1[3]);
            unsigned q2 = umn(umx(s1[2], s1[3]), umn(s2[2], s2[3]));
            m1 = umn(p1, q1);
            m2 = umn(umx(p1, q1), umn(p2, q2));
            #pragma unroll
            for (int m = 16; m <= 32; m <<= 1) {
                unsigned o1 = __shfl_xor(m1, m, 64), o2 = __shfl_xor(m2, m, 64);
                unsigned nm2 = umn(umx(m1, o1), umn(m2, o2));
                m1 = umn(m1, o1); m2 = nm2;
            }
        }
        const float d1m = __uint_as_float(m1 & 0xFFFFFE00u);   // scaled x256
        const float d2m = __uint_as_float(m2 & 0xFFFFFE00u);
        const bool  amb = (d2m - d1m) <= 0.030720f;            // 256 * 1.2e-4

        int bj;
        if (__ballot(amb) == 0ULL) {
            bj = (int)(m1 & 511u);
            if (l < 16) {
                out[IDX_OFF + px] = (float)bj;
                float dd = __uint_as_float((m1 & 0xFFFFFE00u) | 0x100u);
                ls += __fmaf_rn(dd, 0.00390625f, apx - 0.5f);
            }
        } else {
            unsigned k1, k2, k3;
            {
                #define MERGE3(o1,o2,o3, a1,a2,a3, b1,b2,b3)                 \
                    o1 = umn(a1, b1);                                        \
                    o2 = med3u(a1, b1, umn(a2, b2));                         \
                    o3 = umn(umn(a3, b3), umn(umx(a2, b1), umx(a1, b2)));
                unsigned x1,x2,x3, y1,y2,y3;
                MERGE3(x1,x2,x3, s1[0],s2[0],s3[0], s1[1],s2[1],s3[1]);
                MERGE3(y1,y2,y3, s1[2],s2[2],s3[2], s1[3],s2[3],s3[3]);
                MERGE3(k1,k2,k3, x1,x2,x3, y1,y2,y3);
                #undef MERGE3
            }
            float zr[64];
            #pragma unroll
            for (int c = 0; c < 64; ++c) zr[c] = zb[(size_t)c * HW];
            float ap;
            {   // numpy-exact ||z||^2
                float r[8];
                #pragma unroll
                for (int i = 0; i < 8; ++i) r[i] = __fmul_rn(zr[i], zr[i]);
                #pragma unroll
                for (int k = 8; k < 64; k += 8) {
                    #pragma unroll
                    for (int i = 0; i < 8; ++i)
                        r[i] = __fadd_rn(r[i], __fmul_rn(zr[k+i], zr[k+i]));
                }
                ap = __fadd_rn(
                    __fadd_rn(__fadd_rn(r[0],r[1]), __fadd_rn(r[2],r[3])),
                    __fadd_rn(__fadd_rn(r[4],r[5]), __fadd_rn(r[6],r[7])));
            }
            const float thr = d1m + 0.030720f;
            float bd = 3.0e38f; bj = 1023;

            #define RESCORE(K) do {                                               \
                float da_ = __uint_as_float((K) & 0xFFFFFE00u);                   \
                if (da_ <= thr) {                                                 \
                    int j_ = (int)((K) & 511u);                                   \
                    const float* er_ = cb + (size_t)j_ * 64;                      \
                    float a_ = 0.f;                                               \
                    _Pragma("unroll")                                             \
                    for (int c_ = 0; c_ < 64; ++c_)                               \
                        a_ = __fmaf_rn(zr[c_], er_[c_], a_);                      \
                    float dd_ = __fsub_rn(__fadd_rn(ap, eshx[j_]),                \
                                          __fmul_rn(2.0f, a_));                   \
                    if (dd_ < bd || (dd_ == bd && j_ < bj)) { bd = dd_; bj = j_; }\
                }                                                                 \
            } while (0)
            RESCORE(k1); RESCORE(k2); RESCORE(k3);
            #undef RESCORE

            #pragma unroll
            for (int m = 16; m <= 32; m <<= 1) {   // lexicographic (d,j) merge
                float od = __shfl_xor(bd, m, 64);
                int   oj = __shfl_xor(bj, m, 64);
                if (od < bd || (od == bd && oj < bj)) { bd = od; bj = oj; }
            }
            if (l < 16) {
                out[IDX_OFF + px] = (float)bj;
                ls += bd;
            }
        }
        if (pt == 0) bjA = bj; else bjB = bj;
    }

    // ---- z_q write: both tiles together -> full 128B lines ----
    {
        const int pm  = l & 31;
        const int hh  = l >> 5;
        int b0 = __shfl(bjA, pm & 15, 64);
        int b1 = __shfl(bjB, pm & 15, 64);
        const int bjw = (pm >> 4) ? b1 : b0;
        const float* eb = cb + (size_t)bjw * 64;
        float* zq = out + ZQ_OFF + (size_t)bb * (C_DIM * HW) + ((pxw0 + pm) & (HW-1));
        #pragma unroll
        for (int cc = 0; cc < 32; ++cc) {
            int c = hh * 32 + cc;
            zq[(size_t)c * HW] = eb[c];    // 32 px x 2 planes = 2 full lines/instr
        }
    }

    // ---- loss reduce: wave -> block -> ws ----
    #pragma unroll
    for (int off = 32; off; off >>= 1) ls += __shfl_down(ls, off, 64);
    if (l == 0) wsum[wv] = ls;
    __syncthreads();
    if (t == 0) {
        float s = 0.f;
        #pragma unroll
        for (int i = 0; i < 8; ++i) s += wsum[i];
        ws[blockIdx.x] = s;
    }
}

__global__ __launch_bounds__(256) void vq_loss(
    const float* __restrict__ ws, float* __restrict__ out)
{
    __shared__ float sm[4];
    float v = ws[threadIdx.x] + ws[threadIdx.x + 256];   // 512 partials
    #pragma unroll
    for (int off = 32; off; off >>= 1) v += __shfl_down(v, off, 64);
    const int lane = threadIdx.x & 63, wid = threadIdx.x >> 6;
    if (lane == 0) sm[wid] = v;
    __syncthreads();
    if (threadIdx.x == 0)
        out[0] = ((sm[0] + sm[1]) + (sm[2] + sm[3])) * (1.0f / 8388608.0f);
}

extern "C" void kernel_launch(void* const* d_in, const int* in_sizes, int n_in,
                              void* d_out, int out_size, void* d_ws, size_t ws_size,
                              hipStream_t stream)
{
    const float* z  = (const float*)d_in[0];   // 8388608 f32
    const float* cb = (const float*)d_in[1];   // 32768 f32
    float* out = (float*)d_out;
    float* ws  = (float*)d_ws;                 // 512 f32 partials

    vq_main<<<NBLK, TPB, 0, stream>>>(z, cb, out, ws);
    vq_loss<<<1, 256, 0, stream>>>(ws, out);
}